// Round 8
// baseline (446.162 us; speedup 1.0000x reference)
//
#include <hip/hip_runtime.h>

#define NNODES 50000
#define NREL   8
#define HID    64
#define NCLS   16
#define NEDGE  1600000
#define NTGT   8192
#define NBINS  (NNODES * NREL)
#define CHUNK  1024
#define NCHUNK ((NBINS + CHUNK - 1) / CHUNK)   // 391

__device__ __forceinline__ float elu1(float x) { return x > 0.f ? x : expm1f(x); }

__device__ __forceinline__ float wave_sum(float v) {
#pragma unroll
  for (int off = 32; off; off >>= 1) v += __shfl_xor(v, off);
  return v;
}

// --- K1: per-(dst,rel) counts (no slot return needed) ------------------------
__global__ void count_kernel(const int* __restrict__ ei, const int* __restrict__ et,
                             int* __restrict__ cnt) {
  int e4 = (blockIdx.x * blockDim.x + threadIdx.x) * 4;
  if (e4 >= NEDGE) return;
  int4 d = *(const int4*)(ei + NEDGE + e4);
  int4 r = *(const int4*)(et + e4);
  atomicAdd(&cnt[d.x * NREL + r.x], 1);
  atomicAdd(&cnt[d.y * NREL + r.y], 1);
  atomicAdd(&cnt[d.z * NREL + r.z], 1);
  atomicAdd(&cnt[d.w * NREL + r.w], 1);
}

// --- K2a: per-chunk sums -----------------------------------------------------
__global__ void chunk_sum_kernel(const int* __restrict__ cnt, int* __restrict__ csum) {
  __shared__ int sw[4];
  int t = threadIdx.x, lane = t & 63, wid = t >> 6;
  int i = blockIdx.x * CHUNK + t * 4;
  int s = 0;
  if (i < NBINS) { int4 c = *(const int4*)(cnt + i); s = c.x + c.y + c.z + c.w; }
#pragma unroll
  for (int off = 32; off >= 1; off >>= 1) s += __shfl_xor(s, off);
  if (lane == 0) sw[wid] = s;
  __syncthreads();
  if (t == 0) csum[blockIdx.x] = sw[0] + sw[1] + sw[2] + sw[3];
}

// --- K2b: scan the 391 chunk sums (1 block) ---------------------------------
__global__ void scan_csum_kernel(const int* __restrict__ csum, int* __restrict__ cbase) {
  __shared__ int sw[8];
  int t = threadIdx.x, lane = t & 63, wid = t >> 6;  // 512 threads
  int v0 = (t < NCHUNK) ? csum[t] : 0;
  int v = v0;
#pragma unroll
  for (int off = 1; off < 64; off <<= 1) {
    int u = __shfl_up(v, off);
    if (lane >= off) v += u;
  }
  if (lane == 63) sw[wid] = v;
  __syncthreads();
  if (t == 0) {
    int run = 0;
#pragma unroll
    for (int j = 0; j < 8; ++j) { int x = sw[j]; sw[j] = run; run += x; }
  }
  __syncthreads();
  if (t < NCHUNK) cbase[t] = sw[wid] + (v - v0);
}

// --- K2c: per-chunk exclusive scan + base -> binptr AND fill copy ------------
__global__ void scan_write_kernel(const int* __restrict__ cnt, const int* __restrict__ cbase,
                                  int* __restrict__ binptr, int* __restrict__ fill) {
  __shared__ int sw[4];
  int t = threadIdx.x, lane = t & 63, wid = t >> 6;
  int i = blockIdx.x * CHUNK + t * 4;
  int4 c = make_int4(0, 0, 0, 0);
  if (i < NBINS) c = *(const int4*)(cnt + i);
  int p0 = c.x, p1 = p0 + c.y, p2 = p1 + c.z, s = p2 + c.w;
  int v = s;
#pragma unroll
  for (int off = 1; off < 64; off <<= 1) {
    int u = __shfl_up(v, off);
    if (lane >= off) v += u;
  }
  if (lane == 63) sw[wid] = v;
  __syncthreads();
  if (t == 0) {
    int run = 0;
#pragma unroll
    for (int j = 0; j < 4; ++j) { int x = sw[j]; sw[j] = run; run += x; }
  }
  __syncthreads();
  if (i < NBINS) {
    int excl = cbase[blockIdx.x] + sw[wid] + (v - s);
    int4 o = make_int4(excl, excl + p0, excl + p1, excl + p2);
    *(int4*)(binptr + i) = o;
    *(int4*)(fill + i) = o;
  }
  if (blockIdx.x == 0 && t == 0) binptr[NBINS] = NEDGE;
}

// --- K3: scatter — claim slot via atomic on fill; scale from cnt -------------
__global__ void scatter_kernel(const int* __restrict__ ei, const int* __restrict__ et,
                               const int* __restrict__ cnt, int* __restrict__ fill,
                               int2* __restrict__ epo) {
  int e4 = (blockIdx.x * blockDim.x + threadIdx.x) * 4;
  if (e4 >= NEDGE) return;
  int4 sv = *(const int4*)(ei + e4);
  int4 dv = *(const int4*)(ei + NEDGE + e4);
  int4 rv = *(const int4*)(et + e4);
  int srcs[4] = {sv.x, sv.y, sv.z, sv.w};
  int dsts[4] = {dv.x, dv.y, dv.z, dv.w};
  int rels[4] = {rv.x, rv.y, rv.z, rv.w};
#pragma unroll
  for (int j = 0; j < 4; ++j) {
    int bin = dsts[j] * NREL + rels[j];
    int c = cnt[bin];                      // >= 1
    int pos = atomicAdd(&fill[bin], 1);    // any slot order within bin is valid
    epo[pos] = make_int2(rels[j] * NNODES + srcs[j], __float_as_int(1.0f / (float)c));
  }
}

// --- K4: conv1 — wave per node; 64-edge coalesced batch -> SGPR broadcast;
//         16-deep load batching keeps 16 gathers in flight -------------------
__global__ __launch_bounds__(256) void conv1_kernel(
    const int* __restrict__ binptr, const int2* __restrict__ epo,
    const float* __restrict__ w1, const float* __restrict__ root1,
    const float* __restrict__ bias1, float* __restrict__ h1) {
  int wave = blockIdx.x * 4 + (threadIdx.x >> 6);
  if (wave >= NNODES) return;
  int lane = threadIdx.x & 63;
  int b0 = binptr[wave * NREL], b8 = binptr[wave * NREL + NREL];
  float acc = 0.f;
  for (int eb = b0; eb < b8; eb += 64) {
    int mb = min(64, b8 - eb);
    int2 q = epo[eb + min(lane, mb - 1)];
    int j = 0;
    for (; j + 16 <= mb; j += 16) {
      float a[16], sc[16];
#pragma unroll
      for (int u = 0; u < 16; ++u) {
        int idx = __builtin_amdgcn_readlane(q.x, j + u);
        sc[u] = __int_as_float(__builtin_amdgcn_readlane(q.y, j + u));
        a[u] = w1[(((size_t)(unsigned)idx) << 6) + lane];
      }
#pragma unroll
      for (int u = 0; u < 16; ++u) acc = fmaf(a[u], sc[u], acc);
    }
    for (; j + 4 <= mb; j += 4) {
      float a[4], sc[4];
#pragma unroll
      for (int u = 0; u < 4; ++u) {
        int idx = __builtin_amdgcn_readlane(q.x, j + u);
        sc[u] = __int_as_float(__builtin_amdgcn_readlane(q.y, j + u));
        a[u] = w1[(((size_t)(unsigned)idx) << 6) + lane];
      }
#pragma unroll
      for (int u = 0; u < 4; ++u) acc = fmaf(a[u], sc[u], acc);
    }
    for (; j < mb; ++j) {
      int idx = __builtin_amdgcn_readlane(q.x, j);
      float s = __int_as_float(__builtin_amdgcn_readlane(q.y, j));
      acc = fmaf(w1[(((size_t)(unsigned)idx) << 6) + lane], s, acc);
    }
  }
  float v = acc + root1[(wave << 6) + lane] + bias1[lane];
  h1[(wave << 6) + lane] = elu1(v);
}

// --- K5a: conv2 aggregation — wave per (node,rel) bin; 4-deep load batch -----
__global__ __launch_bounds__(256) void conv2a_kernel(
    const int* __restrict__ binptr, const int2* __restrict__ epo,
    const float* __restrict__ h1, float* __restrict__ agg, int nodeBase, int nloc) {
  int wv = blockIdx.x * 4 + (threadIdx.x >> 6);
  if (wv >= nloc * NREL) return;
  int lane = threadIdx.x & 63;
  int r = wv & 7;
  int bin = (nodeBase + (wv >> 3)) * NREL + r;
  int bb = binptr[bin], ee = binptr[bin + 1];
  int rb = r * NNODES;
  float s = 0.f;
  for (int e = bb; e < ee; e += 64) {
    int mb = min(64, ee - e);
    int2 q = epo[e + min(lane, mb - 1)];
    int j = 0;
    for (; j + 4 <= mb; j += 4) {
      float a[4];
#pragma unroll
      for (int u = 0; u < 4; ++u) {
        int i0 = __builtin_amdgcn_readlane(q.x, j + u) - rb;
        a[u] = h1[(((size_t)(unsigned)i0) << 6) + lane];
      }
#pragma unroll
      for (int u = 0; u < 4; ++u) s += a[u];
    }
    for (; j < mb; ++j) {
      int i0 = __builtin_amdgcn_readlane(q.x, j) - rb;
      s += h1[(((size_t)(unsigned)i0) << 6) + lane];
    }
  }
  float out = (ee > bb) ? s * (1.0f / (float)(ee - bb)) : 0.f;
  agg[((size_t)wv << 6) + lane] = out;
}

// --- K5b: conv2 transform + fused linear head --------------------------------
__global__ __launch_bounds__(256, 4) void conv2b_kernel(
    const float* __restrict__ agg, const float* __restrict__ h1,
    const float* __restrict__ w2, const float* __restrict__ root2,
    const float* __restrict__ bias2, const float* __restrict__ lin_w,
    const float* __restrict__ lin_b, float* __restrict__ out, int nodeBase) {
  __shared__ float sW[HID * HID];  // 16 KB
  int t = threadIdx.x, lane = t & 63, wid = t >> 6;
  int ln0 = blockIdx.x * 8 + wid * 2;  // 8 local nodes/block, 2 per wave
  float bz = bias2[lane];
  float o0 = bz, o1 = bz;
  for (int r = 0; r < NREL; ++r) {
    if (r) __syncthreads();
#pragma unroll
    for (int i = 0; i < 4; ++i)
      *(float4*)(sW + t * 4 + i * 1024) = *(const float4*)(w2 + (r << 12) + t * 4 + i * 1024);
    __syncthreads();
    const float* a0 = agg + (((size_t)((ln0 + 0) * NREL + r)) << 6);  // wave-uniform -> s_load
    const float* a1 = agg + (((size_t)((ln0 + 1) * NREL + r)) << 6);
#pragma unroll 16
    for (int k = 0; k < HID; ++k) {
      float w = sW[(k << 6) + lane];
      o0 = fmaf(a0[k], w, o0);
      o1 = fmaf(a1[k], w, o1);
    }
  }
  __syncthreads();
#pragma unroll
  for (int i = 0; i < 4; ++i)
    *(float4*)(sW + t * 4 + i * 1024) = *(const float4*)(root2 + t * 4 + i * 1024);
  __syncthreads();
  int g0 = nodeBase + ln0;
  const float* r0p = h1 + ((size_t)(g0 + 0) << 6);  // wave-uniform -> s_load
  const float* r1p = h1 + ((size_t)(g0 + 1) << 6);
#pragma unroll 16
  for (int k = 0; k < HID; ++k) {
    float w = sW[(k << 6) + lane];
    o0 = fmaf(r0p[k], w, o0);
    o1 = fmaf(r1p[k], w, o1);
  }
  o0 = elu1(o0);
  o1 = elu1(o1);
  // fused head: out[n][c] = sum_k h2[n][k]*lin_w[k][c] + lin_b[c]
  float lw[16];
#pragma unroll
  for (int c4 = 0; c4 < 4; ++c4) {
    float4 v = *(const float4*)(lin_w + lane * NCLS + c4 * 4);
    lw[c4 * 4 + 0] = v.x; lw[c4 * 4 + 1] = v.y; lw[c4 * 4 + 2] = v.z; lw[c4 * 4 + 3] = v.w;
  }
  float res0 = 0.f, res1 = 0.f;
#pragma unroll
  for (int c = 0; c < NCLS; ++c) {
    float s0 = wave_sum(o0 * lw[c]);
    float s1 = wave_sum(o1 * lw[c]);
    if (lane == c) { res0 = s0; res1 = s1; }
  }
  if (lane < NCLS) {
    float lb = lin_b[lane];
    out[(size_t)(g0 + 0) * NCLS + lane] = res0 + lb;
    out[(size_t)(g0 + 1) * NCLS + lane] = res1 + lb;
  }
}

extern "C" void kernel_launch(void* const* d_in, const int* in_sizes, int n_in,
                              void* d_out, int out_size, void* d_ws, size_t ws_size,
                              hipStream_t stream) {
  const int*   ei    = (const int*)d_in[0];
  const int*   et    = (const int*)d_in[1];
  const float* w1    = (const float*)d_in[3];
  const float* root1 = (const float*)d_in[4];
  const float* bias1 = (const float*)d_in[5];
  const float* w2    = (const float*)d_in[6];
  const float* root2 = (const float*)d_in[7];
  const float* bias2 = (const float*)d_in[8];
  const float* lin_w = (const float*)d_in[9];
  const float* lin_b = (const float*)d_in[10];
  float* out = (float*)d_out;

  // Workspace:
  //  A [0,12.8M): cnt (1.6M) lives until scatter; conv1 then overwrites with h1
  //  B binptr (+fill copy) / csum / cbase; C epo 12.8M; D agg (chunk*8*64*4)
  char* ws = (char*)d_ws;
  float* h1     = (float*)ws;
  int*   cnt    = (int*)ws;
  char*  p      = ws + (size_t)NNODES * HID * 4;
  int*   binptr = (int*)p;  p += ((size_t)(NBINS + 1) * 4 + 255) & ~(size_t)255;
  int*   fill   = (int*)p;  p += ((size_t)NBINS * 4 + 255) & ~(size_t)255;
  int*   csum   = (int*)p;  p += ((size_t)NCHUNK * 4 + 255) & ~(size_t)255;
  int*   cbase  = (int*)p;  p += ((size_t)NCHUNK * 4 + 255) & ~(size_t)255;
  int2*  epo    = (int2*)p; p += (size_t)NEDGE * 8;
  float* agg    = (float*)p;
  size_t fixed  = (size_t)(p - ws);
  // Largest conv2 chunk that fits in ws (cascade; ws_size is constant across
  // calls so this is stable under graph capture).
  int chunk = 1024;
  for (int c = NTGT; c >= 2048; c >>= 1)
    if (fixed + (size_t)c * NREL * HID * 4 <= ws_size) { chunk = c; break; }

  hipMemsetAsync(cnt, 0, (size_t)NBINS * sizeof(int), stream);
  count_kernel<<<(NEDGE / 4 + 255) / 256, 256, 0, stream>>>(ei, et, cnt);
  chunk_sum_kernel<<<NCHUNK, 256, 0, stream>>>(cnt, csum);
  scan_csum_kernel<<<1, 512, 0, stream>>>(csum, cbase);
  scan_write_kernel<<<NCHUNK, 256, 0, stream>>>(cnt, cbase, binptr, fill);
  scatter_kernel<<<(NEDGE / 4 + 255) / 256, 256, 0, stream>>>(ei, et, cnt, fill, epo);
  conv1_kernel<<<(NNODES + 3) / 4, 256, 0, stream>>>(binptr, epo, w1, root1, bias1, h1);
  for (int c = 0; c < NTGT / chunk; ++c) {
    conv2a_kernel<<<(chunk * NREL) / 4, 256, 0, stream>>>(binptr, epo, h1, agg, c * chunk, chunk);
    conv2b_kernel<<<chunk / 8, 256, 0, stream>>>(agg, h1, w2, root2, bias2, lin_w, lin_b, out, c * chunk);
  }
}